// Round 5
// baseline (121.385 us; speedup 1.0000x reference)
//
#include <hip/hip_runtime.h>
#include <hip/hip_fp16.h>

#define SEQ 8192
#define NQT 512                // 16-row q-tiles
#define CHUNK 32               // k-tiles (of 16 keys) per wave chunk
#define TOTAL_CHUNKS 4352      // S(512) = sum over qt of ceil((qt+1)/32)

typedef _Float16 half4  __attribute__((ext_vector_type(4)));
typedef _Float16 half8  __attribute__((ext_vector_type(8)));
typedef float   floatx4 __attribute__((ext_vector_type(4)));

// S(n) = chunks for q-tiles 0..n-1 = n + 16a(a-1) + a*r, n = 32a + r
__device__ __forceinline__ int cum_chunks(int n) {
    const int a = n >> 5, r = n & 31;
    return n + 16 * a * (a - 1) + a * r;
}

// ---------------- Kernel 1: QKV projection ----------------
__global__ __launch_bounds__(256) void proj_kernel(
    const float* __restrict__ x,
    const float* __restrict__ Wq, const float* __restrict__ bq,
    const float* __restrict__ Wk, const float* __restrict__ bk,
    const float* __restrict__ Wv, const float* __restrict__ bv,
    _Float16* __restrict__ Q, _Float16* __restrict__ KV)
{
    __shared__ float4 xs[16][17];
    __shared__ float4 wqs[16][17];
    __shared__ float4 wks[16][17];
    __shared__ float4 wvs[16][17];

    const int tid  = threadIdx.x;
    const int r    = tid >> 4;
    const int d    = tid & 15;
    const int row0 = blockIdx.x * 16;

    const int rr  = tid >> 4;
    const int cc4 = tid & 15;
    xs[rr][cc4]  = *(const float4*)(x  + (size_t)row0 * 64 + tid * 4);
    wqs[rr][cc4] = *(const float4*)(Wq + tid * 4);
    wks[rr][cc4] = *(const float4*)(Wk + tid * 4);
    wvs[rr][cc4] = *(const float4*)(Wv + tid * 4);
    __syncthreads();

    float aq = 0.f, ak = 0.f, av = 0.f;
#pragma unroll
    for (int kk = 0; kk < 16; ++kk) {
        const float4 xv = xs[r][kk];
        const float4 q4 = wqs[d][kk];
        const float4 k4 = wks[d][kk];
        const float4 v4 = wvs[d][kk];
        aq += xv.x * q4.x; aq += xv.y * q4.y; aq += xv.z * q4.z; aq += xv.w * q4.w;
        ak += xv.x * k4.x; ak += xv.y * k4.y; ak += xv.z * k4.z; ak += xv.w * k4.w;
        av += xv.x * v4.x; av += xv.y * v4.y; av += xv.z * v4.z; av += xv.w * v4.w;
    }
    aq += bq[d];
    ak += bk[d];
    av += bv[d];
    aq *= 0.36067376022224085f;   // (1/sqrt(16)) * log2(e)

    const int row = row0 + r;
    Q[row * 16 + d] = (_Float16)aq;
    _Float16* kvb = KV + (size_t)blockIdx.x * 512;
    kvb[((d >> 2) * 16 + r) * 8 + (d & 3)]     = (_Float16)ak;
    kvb[((r >> 2) * 16 + d) * 8 + 4 + (r & 3)] = (_Float16)av;
}

// ---------------- Kernel 2: balanced split-K causal flash attention -------
__global__ __launch_bounds__(64) void flash_kernel(
    const _Float16* __restrict__ Q, const _Float16* __restrict__ KV,
    float* __restrict__ partO, float* __restrict__ partL)
{
    const int bp = (TOTAL_CHUNKS - 1) - (int)blockIdx.x;
    int lo = 0, hi = NQT - 1;
#pragma unroll
    for (int it = 0; it < 9; ++it) {          // 2^9 = 512 >= NQT
        const int mid = (lo + hi + 1) >> 1;
        if (cum_chunks(mid) <= bp) lo = mid; else hi = mid - 1;
    }
    const int qt = lo;
    const int c  = bp - cum_chunks(qt);
    const int t0 = c * CHUNK;
    int t1 = t0 + CHUNK;
    if (t1 > qt + 1) t1 = qt + 1;
    const int nd = (t1 > qt) ? qt : t1;       // end of mask-free tiles

    const int L    = threadIdx.x;
    const int m16  = L & 15;
    const int quad = L >> 4;
    const int qrow = qt * 16 + m16;

    const half4 qf = *(const half4*)(Q + (size_t)qrow * 16 + quad * 4);
    const _Float16* kvbase = KV + (size_t)L * 8;   // + kt*512 halfs per tile

    float   l0 = 0.f, l1 = 0.f;
    floatx4 acc0 = {0.f, 0.f, 0.f, 0.f};
    floatx4 acc1 = {0.f, 0.f, 0.f, 0.f};
    const floatx4 z4 = {0.f, 0.f, 0.f, 0.f};

    auto ldkv = [&](int t) -> half8 {
        return *(const half8*)(kvbase + (size_t)t * 512);
    };

    auto body = [&](half8 kv, floatx4& acc, float& ls) {
        const half4 kf = __builtin_shufflevector(kv, kv, 0, 1, 2, 3);
        const half4 vf = __builtin_shufflevector(kv, kv, 4, 5, 6, 7);
        floatx4 s = __builtin_amdgcn_mfma_f32_16x16x16f16(kf, qf, z4, 0, 0, 0);
        const float p0 = __builtin_amdgcn_exp2f(s[0]);
        const float p1 = __builtin_amdgcn_exp2f(s[1]);
        const float p2 = __builtin_amdgcn_exp2f(s[2]);
        const float p3 = __builtin_amdgcn_exp2f(s[3]);
        ls += (p0 + p1) + (p2 + p3);
        const half4 pf = {(_Float16)p0, (_Float16)p1, (_Float16)p2, (_Float16)p3};
        acc = __builtin_amdgcn_mfma_f32_16x16x16f16(vf, pf, acc, 0, 0, 0);
    };

    int kt = t0;
    if (kt + 1 < nd) {
        half8 kv0 = ldkv(kt);
        half8 kv1 = ldkv(kt + 1);
#pragma unroll 2
        for (; kt + 3 < nd; kt += 2) {        // prefetched, dual-acc hot loop
            const half8 n0 = ldkv(kt + 2);
            const half8 n1 = ldkv(kt + 3);
            __builtin_amdgcn_s_setprio(1);
            body(kv0, acc0, l0);
            body(kv1, acc1, l1);
            __builtin_amdgcn_s_setprio(0);
            kv0 = n0; kv1 = n1;
        }
        body(kv0, acc0, l0);
        body(kv1, acc1, l1);
        kt += 2;
    }
    for (; kt < nd; ++kt)
        body(ldkv(kt), acc0, l0);

    if (t1 == qt + 1) {                      // peeled diagonal tile
        const int k0 = qt * 16;
        const half8 kv = ldkv(qt);
        const half4 kf = __builtin_shufflevector(kv, kv, 0, 1, 2, 3);
        const half4 vf = __builtin_shufflevector(kv, kv, 4, 5, 6, 7);
        floatx4 s = __builtin_amdgcn_mfma_f32_16x16x16f16(kf, qf, z4, 0, 0, 0);
#pragma unroll
        for (int r = 0; r < 4; ++r)
            if (k0 + quad * 4 + r > qrow) s[r] = -1.0e30f;  // exp2 -> 0
        const float p0 = __builtin_amdgcn_exp2f(s[0]);
        const float p1 = __builtin_amdgcn_exp2f(s[1]);
        const float p2 = __builtin_amdgcn_exp2f(s[2]);
        const float p3 = __builtin_amdgcn_exp2f(s[3]);
        l1 += (p0 + p1) + (p2 + p3);
        const half4 pf = {(_Float16)p0, (_Float16)p1, (_Float16)p2, (_Float16)p3};
        acc1 = __builtin_amdgcn_mfma_f32_16x16x16f16(vf, pf, acc1, 0, 0, 0);
    }

    floatx4 acc = {acc0[0] + acc1[0], acc0[1] + acc1[1],
                   acc0[2] + acc1[2], acc0[3] + acc1[3]};
    float lsum = l0 + l1;
    lsum += __shfl_xor(lsum, 16);
    lsum += __shfl_xor(lsum, 32);

    *(floatx4*)(partO + (size_t)bp * 256 + m16 * 16 + quad * 4) = acc;
    if (quad == 0) partL[(size_t)bp * 16 + m16] = lsum;
}

// ---------------- Kernel 3: linear merge (coalesced) ----------------------
__global__ __launch_bounds__(256) void merge_kernel(
    const float* __restrict__ partO, const float* __restrict__ partL,
    float* __restrict__ out)
{
    const int qt = blockIdx.x;           // 512 q-tiles
    const int t  = threadIdx.x;          // q = t>>4, d = t&15

    const int base = cum_chunks(qt);
    const int nc   = (qt >> 5) + 1;      // ceil((qt+1)/32)

    const float* po = partO + (size_t)base * 256 + t;
    const float* pl = partL + (size_t)base * 16 + (t >> 4);
    float Ls = 0.f, O = 0.f;
    for (int c = 0; c < nc; ++c, po += 256, pl += 16) {
        O  += *po;
        Ls += *pl;
    }
    out[(size_t)qt * 256 + t] = O / Ls;
}

// MEASUREMENT ROUND 2 (asymmetric): flash launched 5x (idempotent), others 1x.
// Round-4 baseline at this exact config: 84.0 us.
// dur = 84.0 + 4*(flash + gap)  =>  flash ≈ (dur - 84.0)/4.
extern "C" void kernel_launch(void* const* d_in, const int* in_sizes, int n_in,
                              void* d_out, int out_size, void* d_ws, size_t ws_size,
                              hipStream_t stream) {
    const float* x  = (const float*)d_in[0];
    const float* Wq = (const float*)d_in[1];
    const float* bq = (const float*)d_in[2];
    const float* Wk = (const float*)d_in[3];
    const float* bk = (const float*)d_in[4];
    const float* Wv = (const float*)d_in[5];
    const float* bv = (const float*)d_in[6];

    char* ws = (char*)d_ws;
    _Float16* Q     = (_Float16*)(ws);            // 256 KiB
    _Float16* KV    = (_Float16*)(ws + 262144);   // 512 KiB (512 tiles x 1KB)
    float*    partO = (float*)(ws + 786432);      // 4352*256*4 = 4.25 MiB
    float*    partL = (float*)(ws + 786432 + 4456448);  // 4352*16*4 = 272 KiB

    proj_kernel<<<dim3(SEQ / 16), dim3(256), 0, stream>>>(
        x, Wq, bq, Wk, bk, Wv, bv, Q, KV);
    flash_kernel<<<dim3(TOTAL_CHUNKS), dim3(64), 0, stream>>>(
        Q, KV, partO, partL);
    flash_kernel<<<dim3(TOTAL_CHUNKS), dim3(64), 0, stream>>>(
        Q, KV, partO, partL);
    flash_kernel<<<dim3(TOTAL_CHUNKS), dim3(64), 0, stream>>>(
        Q, KV, partO, partL);
    flash_kernel<<<dim3(TOTAL_CHUNKS), dim3(64), 0, stream>>>(
        Q, KV, partO, partL);
    flash_kernel<<<dim3(TOTAL_CHUNKS), dim3(64), 0, stream>>>(
        Q, KV, partO, partL);
    merge_kernel<<<dim3(NQT), dim3(256), 0, stream>>>(
        partO, partL, (float*)d_out);
}

// Round 6
// 83.393 us; speedup vs baseline: 1.4556x; 1.4556x over previous
//
#include <hip/hip_runtime.h>
#include <hip/hip_fp16.h>

#define SEQ 8192
#define NQT 512                // 16-row q-tiles
#define CHUNK 32               // k-tiles (of 16 keys) per wave chunk
#define TOTAL_CHUNKS 4352      // S(512) = sum over qt of ceil((qt+1)/32)

typedef _Float16 half4  __attribute__((ext_vector_type(4)));
typedef _Float16 half8  __attribute__((ext_vector_type(8)));
typedef float   floatx4 __attribute__((ext_vector_type(4)));

// S(n) = chunks for q-tiles 0..n-1 = n + 16a(a-1) + a*r, n = 32a + r
__device__ __forceinline__ int cum_chunks(int n) {
    const int a = n >> 5, r = n & 31;
    return n + 16 * a * (a - 1) + a * r;
}

// ---------------- Kernel 1: QKV projection ----------------
__global__ __launch_bounds__(256) void proj_kernel(
    const float* __restrict__ x,
    const float* __restrict__ Wq, const float* __restrict__ bq,
    const float* __restrict__ Wk, const float* __restrict__ bk,
    const float* __restrict__ Wv, const float* __restrict__ bv,
    _Float16* __restrict__ Q, _Float16* __restrict__ KV)
{
    __shared__ float4 xs[16][17];
    __shared__ float4 wqs[16][17];
    __shared__ float4 wks[16][17];
    __shared__ float4 wvs[16][17];

    const int tid  = threadIdx.x;
    const int r    = tid >> 4;
    const int d    = tid & 15;
    const int row0 = blockIdx.x * 16;

    const int rr  = tid >> 4;
    const int cc4 = tid & 15;
    xs[rr][cc4]  = *(const float4*)(x  + (size_t)row0 * 64 + tid * 4);
    wqs[rr][cc4] = *(const float4*)(Wq + tid * 4);
    wks[rr][cc4] = *(const float4*)(Wk + tid * 4);
    wvs[rr][cc4] = *(const float4*)(Wv + tid * 4);
    __syncthreads();

    float aq = 0.f, ak = 0.f, av = 0.f;
#pragma unroll
    for (int kk = 0; kk < 16; ++kk) {
        const float4 xv = xs[r][kk];
        const float4 q4 = wqs[d][kk];
        const float4 k4 = wks[d][kk];
        const float4 v4 = wvs[d][kk];
        aq += xv.x * q4.x; aq += xv.y * q4.y; aq += xv.z * q4.z; aq += xv.w * q4.w;
        ak += xv.x * k4.x; ak += xv.y * k4.y; ak += xv.z * k4.z; ak += xv.w * k4.w;
        av += xv.x * v4.x; av += xv.y * v4.y; av += xv.z * v4.z; av += xv.w * v4.w;
    }
    aq += bq[d];
    ak += bk[d];
    av += bv[d];
    aq *= 0.36067376022224085f;   // (1/sqrt(16)) * log2(e)

    const int row = row0 + r;
    Q[row * 16 + d] = (_Float16)aq;
    _Float16* kvb = KV + (size_t)blockIdx.x * 512;
    kvb[((d >> 2) * 16 + r) * 8 + (d & 3)]     = (_Float16)ak;
    kvb[((r >> 2) * 16 + d) * 8 + 4 + (r & 3)] = (_Float16)av;
}

// ---------------- Kernel 2: balanced split-K causal flash attention -------
// One wave per chunk of <=32 k-tiles. K+V fragments interleaved: ONE
// global_load_dwordx4 per tile body. 4-deep software pipeline (prefetch
// distance = 4 bodies ~ 300 cyc of issue) to cover loaded-L2 latency that
// the old 2-deep pipeline left exposed (round-5 isolation: 175 cyc/body
// issued vs ~75 cyc issue work = latency-bound).
// acc0/acc1 parity per kt identical to the 2-deep version -> bit-identical.
__global__ __launch_bounds__(64) void flash_kernel(
    const _Float16* __restrict__ Q, const _Float16* __restrict__ KV,
    float* __restrict__ partO, float* __restrict__ partL)
{
    const int bp = (TOTAL_CHUNKS - 1) - (int)blockIdx.x;
    int lo = 0, hi = NQT - 1;
#pragma unroll
    for (int it = 0; it < 9; ++it) {          // 2^9 = 512 >= NQT
        const int mid = (lo + hi + 1) >> 1;
        if (cum_chunks(mid) <= bp) lo = mid; else hi = mid - 1;
    }
    const int qt = lo;
    const int c  = bp - cum_chunks(qt);
    const int t0 = c * CHUNK;
    int t1 = t0 + CHUNK;
    if (t1 > qt + 1) t1 = qt + 1;
    const int nd = (t1 > qt) ? qt : t1;       // end of mask-free tiles

    const int L    = threadIdx.x;
    const int m16  = L & 15;
    const int quad = L >> 4;
    const int qrow = qt * 16 + m16;

    const half4 qf = *(const half4*)(Q + (size_t)qrow * 16 + quad * 4);
    const _Float16* kvbase = KV + (size_t)L * 8;   // + kt*512 halfs per tile

    float   l0 = 0.f, l1 = 0.f;
    floatx4 acc0 = {0.f, 0.f, 0.f, 0.f};
    floatx4 acc1 = {0.f, 0.f, 0.f, 0.f};
    const floatx4 z4 = {0.f, 0.f, 0.f, 0.f};

    auto ldkv = [&](int t) -> half8 {
        return *(const half8*)(kvbase + (size_t)t * 512);
    };

    auto body = [&](half8 kv, floatx4& acc, float& ls) {
        const half4 kf = __builtin_shufflevector(kv, kv, 0, 1, 2, 3);
        const half4 vf = __builtin_shufflevector(kv, kv, 4, 5, 6, 7);
        floatx4 s = __builtin_amdgcn_mfma_f32_16x16x16f16(kf, qf, z4, 0, 0, 0);
        const float p0 = __builtin_amdgcn_exp2f(s[0]);
        const float p1 = __builtin_amdgcn_exp2f(s[1]);
        const float p2 = __builtin_amdgcn_exp2f(s[2]);
        const float p3 = __builtin_amdgcn_exp2f(s[3]);
        ls += (p0 + p1) + (p2 + p3);
        const half4 pf = {(_Float16)p0, (_Float16)p1, (_Float16)p2, (_Float16)p3};
        acc = __builtin_amdgcn_mfma_f32_16x16x16f16(vf, pf, acc, 0, 0, 0);
    };

    int kt = t0;
    if (nd - kt >= 4) {
        half8 b0 = ldkv(kt);
        half8 b1 = ldkv(kt + 1);
        half8 b2 = ldkv(kt + 2);
        half8 b3 = ldkv(kt + 3);
        for (; kt + 7 < nd; kt += 4) {        // 4-deep pipelined hot loop
            const half8 n0 = ldkv(kt + 4);
            const half8 n1 = ldkv(kt + 5);
            const half8 n2 = ldkv(kt + 6);
            const half8 n3 = ldkv(kt + 7);
            __builtin_amdgcn_s_setprio(1);
            body(b0, acc0, l0);
            body(b1, acc1, l1);
            body(b2, acc0, l0);
            body(b3, acc1, l1);
            __builtin_amdgcn_s_setprio(0);
            b0 = n0; b1 = n1; b2 = n2; b3 = n3;
        }
        body(b0, acc0, l0);
        body(b1, acc1, l1);
        body(b2, acc0, l0);
        body(b3, acc1, l1);
        kt += 4;
    }
    for (; kt + 1 < nd; kt += 2) {            // short-chunk / tail pairs
        body(ldkv(kt),     acc0, l0);
        body(ldkv(kt + 1), acc1, l1);
    }
    if (kt < nd)
        body(ldkv(kt), acc0, l0);

    if (t1 == qt + 1) {                      // peeled diagonal tile
        const int k0 = qt * 16;
        const half8 kv = ldkv(qt);
        const half4 kf = __builtin_shufflevector(kv, kv, 0, 1, 2, 3);
        const half4 vf = __builtin_shufflevector(kv, kv, 4, 5, 6, 7);
        floatx4 s = __builtin_amdgcn_mfma_f32_16x16x16f16(kf, qf, z4, 0, 0, 0);
#pragma unroll
        for (int r = 0; r < 4; ++r)
            if (k0 + quad * 4 + r > qrow) s[r] = -1.0e30f;  // exp2 -> 0
        const float p0 = __builtin_amdgcn_exp2f(s[0]);
        const float p1 = __builtin_amdgcn_exp2f(s[1]);
        const float p2 = __builtin_amdgcn_exp2f(s[2]);
        const float p3 = __builtin_amdgcn_exp2f(s[3]);
        l1 += (p0 + p1) + (p2 + p3);
        const half4 pf = {(_Float16)p0, (_Float16)p1, (_Float16)p2, (_Float16)p3};
        acc1 = __builtin_amdgcn_mfma_f32_16x16x16f16(vf, pf, acc1, 0, 0, 0);
    }

    floatx4 acc = {acc0[0] + acc1[0], acc0[1] + acc1[1],
                   acc0[2] + acc1[2], acc0[3] + acc1[3]};
    float lsum = l0 + l1;
    lsum += __shfl_xor(lsum, 16);
    lsum += __shfl_xor(lsum, 32);

    *(floatx4*)(partO + (size_t)bp * 256 + m16 * 16 + quad * 4) = acc;
    if (quad == 0) partL[(size_t)bp * 16 + m16] = lsum;
}

// ---------------- Kernel 3: linear merge (coalesced) ----------------------
__global__ __launch_bounds__(256) void merge_kernel(
    const float* __restrict__ partO, const float* __restrict__ partL,
    float* __restrict__ out)
{
    const int qt = blockIdx.x;           // 512 q-tiles
    const int t  = threadIdx.x;          // q = t>>4, d = t&15

    const int base = cum_chunks(qt);
    const int nc   = (qt >> 5) + 1;      // ceil((qt+1)/32)

    const float* po = partO + (size_t)base * 256 + t;
    const float* pl = partL + (size_t)base * 16 + (t >> 4);
    float Ls = 0.f, O = 0.f;
    for (int c = 0; c < nc; ++c, po += 256, pl += 16) {
        O  += *po;
        Ls += *pl;
    }
    out[(size_t)qt * 256 + t] = O / Ls;
}

extern "C" void kernel_launch(void* const* d_in, const int* in_sizes, int n_in,
                              void* d_out, int out_size, void* d_ws, size_t ws_size,
                              hipStream_t stream) {
    const float* x  = (const float*)d_in[0];
    const float* Wq = (const float*)d_in[1];
    const float* bq = (const float*)d_in[2];
    const float* Wk = (const float*)d_in[3];
    const float* bk = (const float*)d_in[4];
    const float* Wv = (const float*)d_in[5];
    const float* bv = (const float*)d_in[6];

    char* ws = (char*)d_ws;
    _Float16* Q     = (_Float16*)(ws);            // 256 KiB
    _Float16* KV    = (_Float16*)(ws + 262144);   // 512 KiB (512 tiles x 1KB)
    float*    partO = (float*)(ws + 786432);      // 4352*256*4 = 4.25 MiB
    float*    partL = (float*)(ws + 786432 + 4456448);  // 4352*16*4 = 272 KiB

    proj_kernel<<<dim3(SEQ / 16), dim3(256), 0, stream>>>(
        x, Wq, bq, Wk, bk, Wv, bv, Q, KV);
    flash_kernel<<<dim3(TOTAL_CHUNKS), dim3(64), 0, stream>>>(
        Q, KV, partO, partL);
    merge_kernel<<<dim3(NQT), dim3(256), 0, stream>>>(
        partO, partL, (float*)d_out);
}